// Round 15
// baseline (119.847 us; speedup 1.0000x reference)
//
#include <hip/hip_runtime.h>
#include <hip/hip_bf16.h>
#include <math.h>

typedef float f32x4 __attribute__((ext_vector_type(4)));
typedef float f32x16 __attribute__((ext_vector_type(16)));
typedef __bf16 b16x8 __attribute__((ext_vector_type(8)));
typedef __bf16 b16x4 __attribute__((ext_vector_type(4)));
typedef unsigned int u32x2 __attribute__((ext_vector_type(2)));
typedef unsigned int u32x4 __attribute__((ext_vector_type(4)));

#define L2E 1.44269504088896340736f

// ---------------------------------------------------------------- weights prep
__global__ void prep_weights(const float* tw, const float* pw, const float* gw,
                             const float* ow, __bf16* Wp, __bf16* OWp) {
    int idx = blockIdx.x * 256 + threadIdx.x;
    if (idx < 640 * 256) {
        int m = idx >> 8, k = idx & 255;
        float v;
        if (m < 256)      { int o = ((m & 63) << 2) + (m >> 6);            v = tw[o * 256 + k]; }
        else if (m < 512) { int mm = m - 256; int o = ((mm & 63) << 2) + (mm >> 6); v = pw[o * 256 + k]; }
        else              { int mm = m - 512; int o = ((mm & 31) << 2) + (mm >> 5); v = gw[o * 256 + k]; }
        Wp[idx] = (__bf16)v;
    } else {
        int j = idx - 640 * 256;
        if (j < 256 * 128) {
            int m = j >> 7, c = j & 127;
            int o = ((c & 31) << 2) + (c >> 5);
            OWp[j] = (__bf16)ow[m * 128 + o];
        }
    }
}

// ---------------- fused conv GEMM + transpose + theta-stats + POOLING epilogue
__global__ __launch_bounds__(256) void conv_gemm(const __bf16* __restrict__ Wp,
                                                 const float* __restrict__ x,
                                                 __bf16* theta_t, __bf16* phk, __bf16* gT,
                                                 float* tp1, float* tp2,
                                                 float* pp1, float* pp2,
                                                 float* gp1, float* gp2) {
    __shared__ __align__(16) char smem[38912];
    __bf16* Al = (__bf16*)smem;               // [128][40]
    __bf16* Bl = (__bf16*)(smem + 10240);     // [128][40]
    __bf16* Pl = (__bf16*)smem;               // pooled-phase alias: [128][136]
    float* S1w = (float*)(smem + 34816);      // [4][128]
    float* S2w = (float*)(smem + 36864);      // [4][128]
    int b = blockIdx.z, mt = blockIdx.y, nt = blockIdx.x;
    int tid = threadIdx.x, l = tid & 63, w = tid >> 6;
    int wm = w >> 1, wn = w & 1, lr = l & 15, lg = l >> 4;
    f32x4 acc[4][4];
#pragma unroll
    for (int i = 0; i < 4; i++)
#pragma unroll
        for (int j = 0; j < 4; j++)
#pragma unroll
            for (int r = 0; r < 4; r++) acc[i][j][r] = 0.f;
    const __bf16* Ag = Wp + (size_t)mt * 128 * 256;
    const float* Bx = x + (size_t)b * 1048576 + nt * 128;
    int srow = tid >> 2, scol = (tid & 3) * 8;
    int bn = tid & 127, bk0 = (tid >> 7) * 8;
    b16x8 aR[2];
    float xr[2][8];
#pragma unroll
    for (int hh = 0; hh < 2; hh++)
        aR[hh] = *(const b16x8*)&Ag[(size_t)(srow + hh * 64) * 256 + scol];
#pragma unroll
    for (int u = 0; u < 2; u++)
#pragma unroll
        for (int e = 0; e < 8; e++)
            xr[u][e] = Bx[(size_t)(bk0 + u * 16 + e) * 4096 + bn];
    for (int k0 = 0; k0 < 256; k0 += 32) {
        if (k0) __syncthreads();
#pragma unroll
        for (int hh = 0; hh < 2; hh++)
            *(b16x8*)&Al[(srow + hh * 64) * 40 + scol] = aR[hh];
#pragma unroll
        for (int u = 0; u < 2; u++) {
            b16x8 v;
#pragma unroll
            for (int e = 0; e < 8; e++) v[e] = (__bf16)xr[u][e];
            *(b16x8*)&Bl[bn * 40 + bk0 + u * 16] = v;
        }
        __syncthreads();
        if (k0 < 224) {
#pragma unroll
            for (int hh = 0; hh < 2; hh++)
                aR[hh] = *(const b16x8*)&Ag[(size_t)(srow + hh * 64) * 256 + k0 + 32 + scol];
#pragma unroll
            for (int u = 0; u < 2; u++)
#pragma unroll
                for (int e = 0; e < 8; e++)
                    xr[u][e] = Bx[(size_t)(k0 + 32 + bk0 + u * 16 + e) * 4096 + bn];
        }
        int ko = lg * 8;
        b16x8 af[4], bfr[4];
#pragma unroll
        for (int i = 0; i < 4; i++) af[i]  = *(b16x8*)&Al[(wm * 64 + i * 16 + lr) * 40 + ko];
#pragma unroll
        for (int i = 0; i < 4; i++) bfr[i] = *(b16x8*)&Bl[(wn * 64 + i * 16 + lr) * 40 + ko];
#pragma unroll
        for (int i = 0; i < 4; i++)
#pragma unroll
            for (int j = 0; j < 4; j++)
                acc[i][j] = __builtin_amdgcn_mfma_f32_16x16x32_bf16(af[i], bfr[j], acc[i][j], 0, 0, 0);
    }
    if (mt < 2) {
        // ---- theta: stats partials + full-res transposed write
#pragma unroll
        for (int i = 0; i < 4; i++) {
            float s1v[4], s2v[4];
#pragma unroll
            for (int r = 0; r < 4; r++) {
                float a0 = acc[i][0][r], a1 = acc[i][1][r], a2 = acc[i][2][r], a3 = acc[i][3][r];
                s1v[r] = (a0 + a1) + (a2 + a3);
                s2v[r] = (a0 * a0 + a1 * a1) + (a2 * a2 + a3 * a3);
            }
#pragma unroll
            for (int msk = 1; msk < 16; msk <<= 1)
#pragma unroll
                for (int r = 0; r < 4; r++) {
                    s1v[r] += __shfl_xor(s1v[r], msk, 64);
                    s2v[r] += __shfl_xor(s2v[r], msk, 64);
                }
            if (lr == 0) {
                int row = (b * 32 + nt) * 2 + wn;
#pragma unroll
                for (int r = 0; r < 4; r++) {
                    int ch = mt * 128 + wm * 64 + i * 16 + lg * 4 + r;
                    tp1[row * 256 + ch] = s1v[r];
                    tp2[row * 256 + ch] = s2v[r];
                }
            }
        }
        int rbase = lg * 4;
#pragma unroll
        for (int i = 0; i < 4; i++) {
            int m = mt * 128 + wm * 64 + i * 16 + rbase;
#pragma unroll
            for (int j = 0; j < 4; j++) {
                int p = nt * 128 + wn * 64 + j * 16 + lr;
                b16x4 v;
#pragma unroll
                for (int r = 0; r < 4; r++) v[r] = (__bf16)acc[i][j][r];
                *(b16x4*)&theta_t[((size_t)b * 4096 + p) * 256 + m] = v;
            }
        }
    } else {
        // ---- phi/g: pool 2x2 in LDS, write pooled fragment-order + stats
        __syncthreads();                       // Al/Bl dead -> reuse as Pl
        int rbase = lg * 4;
#pragma unroll
        for (int i = 0; i < 4; i++) {
            int ch = wm * 64 + i * 16 + rbase;
#pragma unroll
            for (int j = 0; j < 4; j++) {
                int p = wn * 64 + j * 16 + lr;
                b16x4 v;
#pragma unroll
                for (int r = 0; r < 4; r++) v[r] = (__bf16)acc[i][j][r];
                *(b16x4*)&Pl[p * 136 + ch] = v;
            }
        }
        __syncthreads();
        int o = tid & 15, tq = tid >> 4;       // o: channel octet; tq: q-pair group
        float a1[8], a2[8];
#pragma unroll
        for (int e = 0; e < 8; e++) { a1[e] = 0.f; a2[e] = 0.f; }
        b16x8 pooled[2];
#pragma unroll
        for (int ss = 0; ss < 2; ss++) {
            int xq = tq * 2 + ss;
            b16x8 v0 = *(b16x8*)&Pl[(2 * xq) * 136 + o * 8];
            b16x8 v1 = *(b16x8*)&Pl[(2 * xq + 1) * 136 + o * 8];
            b16x8 v2 = *(b16x8*)&Pl[(64 + 2 * xq) * 136 + o * 8];
            b16x8 v3 = *(b16x8*)&Pl[(65 + 2 * xq) * 136 + o * 8];
            b16x8 mv;
#pragma unroll
            for (int e = 0; e < 8; e++) {
                float m = fmaxf(fmaxf((float)v0[e], (float)v1[e]), fmaxf((float)v2[e], (float)v3[e]));
                mv[e] = (__bf16)m; a1[e] += m; a2[e] += m * m;
            }
            pooled[ss] = mv;
        }
#pragma unroll
        for (int e = 0; e < 8; e++) {
            a1[e] += __shfl_xor(a1[e], 16, 64); a1[e] += __shfl_xor(a1[e], 32, 64);
            a2[e] += __shfl_xor(a2[e], 16, 64); a2[e] += __shfl_xor(a2[e], 32, 64);
        }
        if ((tid & 63) < 16) {
#pragma unroll
            for (int e = 0; e < 8; e++) {
                S1w[w * 128 + o * 8 + e] = a1[e];
                S2w[w * 128 + o * 8 + e] = a2[e];
            }
        }
        __syncthreads();
        int cc = nt >> 1;
        if (mt < 4) {
            if (tid < 128) {
                float s1 = S1w[tid] + S1w[128 + tid] + S1w[256 + tid] + S1w[384 + tid];
                float s2 = S2w[tid] + S2w[128 + tid] + S2w[256 + tid] + S2w[384 + tid];
                pp1[(size_t)(b * 32 + nt) * 256 + (mt - 2) * 128 + tid] = s1;
                pp2[(size_t)(b * 32 + nt) * 256 + (mt - 2) * 128 + tid] = s2;
            }
            int hh = (mt - 2) * 2 + (o >> 3), slot = o & 7, bh = b * 4 + hh;
#pragma unroll
            for (int ss = 0; ss < 2; ss++) {
                int key = (nt & 1) * 32 + tq * 2 + ss;
                *(b16x8*)&phk[((((size_t)bh * 16 + cc) * 8 + slot) * 64 + key) * 8] = pooled[ss];
            }
        } else {
            if (tid < 128) {
                float s1 = S1w[tid] + S1w[128 + tid] + S1w[256 + tid] + S1w[384 + tid];
                float s2 = S2w[tid] + S2w[128 + tid] + S2w[256 + tid] + S2w[384 + tid];
                gp1[(size_t)(b * 32 + nt) * 128 + tid] = s1;
                gp2[(size_t)(b * 32 + nt) * 128 + tid] = s2;
            }
            // transpose pooled [32 q][128 ch] -> V-fragment order [seg][ch][8 keys]
            __bf16* Pg = Pl;
#pragma unroll
            for (int ss = 0; ss < 2; ss++)
                *(b16x8*)&Pg[(tq * 2 + ss) * 136 + o * 8] = pooled[ss];
            __syncthreads();
            int ch = tid & 127, kg = tid >> 7;
            int hh = ch >> 5, c32 = ch & 31, bh = b * 4 + hh;
#pragma unroll
            for (int gi = 0; gi < 2; gi++) {
                int g2 = kg * 2 + gi;
                b16x8 v;
#pragma unroll
                for (int e = 0; e < 8; e++) v[e] = Pg[(g2 * 8 + e) * 136 + ch];
                int seg = (nt & 1) * 4 + g2;
                *(b16x8*)&gT[((((size_t)bh * 16 + cc) * 8 + seg) * 32 + c32) * 8] = v;
            }
        }
    }
}

// --------------------------------------- sum partials, fold mean/rstd + affine into scale/bias
__global__ void finalize_stats(const float* tp1, const float* tp2, const float* pp1,
                               const float* pp2, const float* gp1, const float* gp2,
                               const float* ntw, const float* ntb, const float* npw,
                               const float* npb, const float* ngw, const float* ngb,
                               float* sct, float* bit, float* scp, float* bip,
                               float* scg, float* big) {
    int idx = blockIdx.x * 256 + threadIdx.x;
    if (idx >= 8 * 640) return;
    int b = idx / 640, c = idx % 640;
    if (c < 256) {
        float s1 = 0.f, s2 = 0.f;
        for (int i = 0; i < 64; i++) { s1 += tp1[(b * 64 + i) * 256 + c]; s2 += tp2[(b * 64 + i) * 256 + c]; }
        float n = 4096.f;
        float m = s1 / n, v = s2 / n - m * m;
        float r = rsqrtf(v + 1e-5f);
        int o = ((c & 63) << 2) + (c >> 6);
        float wv = ntw[o], bv = ntb[o];
        sct[b * 256 + c] = r * wv * L2E;               // log2e folded for exp2-softmax
        bit[b * 256 + c] = (bv - m * r * wv) * L2E;
    } else if (c < 512) {
        int cc = c - 256;
        float s1 = 0.f, s2 = 0.f;
        for (int i = 0; i < 32; i++) { s1 += pp1[(b * 32 + i) * 256 + cc]; s2 += pp2[(b * 32 + i) * 256 + cc]; }
        float n = 1024.f;
        float m = s1 / n, v = s2 / n - m * m;
        float r = rsqrtf(v + 1e-5f);
        int o = ((cc & 63) << 2) + (cc >> 6);
        float wv = npw[o], bv = npb[o];
        scp[b * 256 + cc] = r * wv; bip[b * 256 + cc] = bv - m * r * wv;
    } else {
        int cc = c - 512;
        float s1 = 0.f, s2 = 0.f;
        for (int i = 0; i < 32; i++) { s1 += gp1[(b * 32 + i) * 128 + cc]; s2 += gp2[(b * 32 + i) * 128 + cc]; }
        float n = 1024.f;
        float m = s1 / n, v = s2 / n - m * m;
        float r = rsqrtf(v + 1e-5f);
        int o = ((cc & 31) << 2) + (cc >> 5);
        float wv = ngw[o], bv = ngb[o];
        scg[b * 128 + cc] = r * wv; big[b * 128 + cc] = bv - m * r * wv;
    }
}

// ------------------------------------------- flash attention: R13 structure, cq via acc-init
// K is RAW pooled phi. scp folds into Q; K-norm bias enters as the QK accumulator
// INIT (cqv[m] broadcast) — no per-element adds, single s chain live (no spill).
__global__ __launch_bounds__(256, 2) void attn(const __bf16* __restrict__ theta_t,
                                               const __bf16* __restrict__ phk,
                                               const __bf16* __restrict__ gTz,
                                               const float* __restrict__ sct,
                                               const float* __restrict__ bit,
                                               const float* __restrict__ scp,
                                               const float* __restrict__ bip,
                                               const float* __restrict__ scg,
                                               const float* __restrict__ big,
                                               __bf16* __restrict__ o_mid) {
    int bid = blockIdx.x;
    int idx = bid >> 3;
    int bh = (bid & 7) * 4 + (idx >> 4), qt = idx & 15;   // XCD-clustered: 4 bh per XCD
    int b = bh >> 2, h = bh & 3;
    int tid = threadIdx.x, w = tid >> 6, lane = tid & 63;
    int l31 = lane & 31, hi = lane >> 5;
    int qb = qt * 256 + w * 64;

    // Q fragments: thn = sct*theta+bit (log2e folded); qf = thn*scp; cq = sum thn*bip
    b16x8 qf[2][4];
    f32x16 cqv[2];
#pragma unroll
    for (int m = 0; m < 2; m++) {
        float cq = 0.f;
        int q = qb + m * 32 + l31;
        const __bf16* qp = theta_t + ((size_t)b * 4096 + q) * 256 + h * 64;
#pragma unroll
        for (int st = 0; st < 4; st++) {
            int cb = st * 16 + hi * 8;
            b16x8 raw = *(const b16x8*)&qp[cb];
            b16x8 nv;
#pragma unroll
            for (int e = 0; e < 8; e++) {
                int cix = b * 256 + h * 64 + cb + e;
                float thn = (float)raw[e] * sct[cix] + bit[cix];
                cq += thn * bip[cix];
                nv[e] = (__bf16)(thn * scp[cix]);
            }
            qf[m][st] = nv;
        }
        cq += __shfl_xor(cq, 32, 64);   // partner half's 32 channels
#pragma unroll
        for (int r = 0; r < 16; r++) cqv[m][r] = cq;
    }

    const __bf16* Kg = phk + (size_t)bh * 65536 + (size_t)hi * 512 + (size_t)l31 * 8;
    const __bf16* Vg = gTz + (size_t)bh * 32768 + (size_t)hi * 256 + (size_t)l31 * 8;

    f32x16 oacc[2];
    float l_run[2] = {0.f, 0.f};
#pragma unroll
    for (int m = 0; m < 2; m++)
#pragma unroll
        for (int r = 0; r < 16; r++) oacc[m][r] = 0.f;

    b16x8 akA[2][4], avA[4], akB[2][4], avB[4];

#define LOADK(dst, c) { _Pragma("unroll") for (int kf = 0; kf < 2; kf++) \
    _Pragma("unroll") for (int st = 0; st < 4; st++) \
        dst[kf][st] = *(const b16x8*)&Kg[(size_t)(c) * 4096 + st * 1024 + kf * 256]; }
#define LOADV(dst, c) { _Pragma("unroll") for (int js = 0; js < 4; js++) \
    dst[js] = *(const b16x8*)&Vg[(size_t)(c) * 2048 + js * 512]; }
#define COMPUTE(ak, av) { \
    _Pragma("unroll") for (int m = 0; m < 2; m++) { \
        _Pragma("unroll") for (int kf = 0; kf < 2; kf++) { \
            f32x16 s = __builtin_amdgcn_mfma_f32_32x32x16_bf16(ak[kf][0], qf[m][0], cqv[m], 0, 0, 0); \
            _Pragma("unroll") for (int st = 1; st < 4; st++) \
                s = __builtin_amdgcn_mfma_f32_32x32x16_bf16(ak[kf][st], qf[m][st], s, 0, 0, 0); \
            float p0s = 0.f, p1s = 0.f, p2s = 0.f, p3s = 0.f; \
            _Pragma("unroll") for (int r = 0; r < 16; r += 4) { \
                float p0 = __builtin_amdgcn_exp2f(s[r]); \
                float p1 = __builtin_amdgcn_exp2f(s[r + 1]); \
                float p2 = __builtin_amdgcn_exp2f(s[r + 2]); \
                float p3 = __builtin_amdgcn_exp2f(s[r + 3]); \
                s[r] = p0; s[r + 1] = p1; s[r + 2] = p2; s[r + 3] = p3; \
                p0s += p0; p1s += p1; p2s += p2; p3s += p3; \
            } \
            l_run[m] += (p0s + p1s) + (p2s + p3s); \
            _Pragma("unroll") for (int hh2 = 0; hh2 < 2; hh2++) { \
                b16x4 A4, B4; \
                _Pragma("unroll") for (int e = 0; e < 4; e++) { \
                    A4[e] = (__bf16)s[hh2 * 8 + e]; B4[e] = (__bf16)s[hh2 * 8 + 4 + e]; } \
                u32x2 a2 = __builtin_bit_cast(u32x2, A4); \
                u32x2 b2 = __builtin_bit_cast(u32x2, B4); \
                u32x2 q0 = __builtin_amdgcn_permlane32_swap(a2[0], b2[0], false, false); \
                u32x2 q1 = __builtin_amdgcn_permlane32_swap(a2[1], b2[1], false, false); \
                u32x4 pd = {q0[0], q1[0], q0[1], q1[1]}; \
                b16x8 pf = __builtin_bit_cast(b16x8, pd); \
                oacc[m] = __builtin_amdgcn_mfma_f32_32x32x16_bf16(av[kf * 2 + hh2], pf, oacc[m], 0, 0, 0); \
            } \
        } \
    } }

    LOADK(akA, 0) LOADV(avA, 0)
#pragma unroll 1
    for (int c = 0; c < 16; c += 2) {
        LOADK(akB, c + 1) LOADV(avB, c + 1)
        COMPUTE(akA, avA)
        if (c + 2 < 16) { LOADK(akA, c + 2) LOADV(avA, c + 2) }
        COMPUTE(akB, avB)
    }
#undef LOADK
#undef LOADV
#undef COMPUTE

    // epilogue: out = scg*(PV/l) + big  (V affine via softmax-sum identity)
#pragma unroll
    for (int m = 0; m < 2; m++) {
        float lr = l_run[m] + __shfl_xor(l_run[m], 32, 64);
        float rl = 1.0f / lr;
        int q = qb + m * 32 + l31;
#pragma unroll
        for (int rr = 0; rr < 4; rr++) {
            b16x4 v;
#pragma unroll
            for (int e = 0; e < 4; e++) {
                int ci = b * 128 + h * 32 + rr * 8 + hi * 4 + e;
                v[e] = (__bf16)(oacc[m][rr * 4 + e] * rl * scg[ci] + big[ci]);
            }
            *(b16x4*)&o_mid[((size_t)b * 4096 + q) * 128 + h * 32 + rr * 8 + hi * 4] = v;
        }
    }
}

// --------------------------------------------- final conv + residual: out = gamma*o + x
__global__ __launch_bounds__(256) void out_gemm(const __bf16* __restrict__ OWp,
                                                const __bf16* __restrict__ o_mid,
                                                const float* __restrict__ x,
                                                const float* gamma, float* out) {
    int b = blockIdx.z, mt = blockIdx.y, nt = blockIdx.x;
    __shared__ __bf16 Al[128 * 40];
    __shared__ __bf16 Bl[128 * 40];
    int tid = threadIdx.x, l = tid & 63, w = tid >> 6;
    int wm = w >> 1, wn = w & 1, lr = l & 15, lg = l >> 4;
    f32x4 acc[4][4];
#pragma unroll
    for (int i = 0; i < 4; i++)
#pragma unroll
        for (int j = 0; j < 4; j++)
#pragma unroll
            for (int r = 0; r < 4; r++) acc[i][j][r] = 0.f;
    const __bf16* Ag = OWp + (size_t)mt * 128 * 128;
    const __bf16* Bg = o_mid + ((size_t)b * 4096 + nt * 128) * 128;
    int srow = tid >> 2, scol = (tid & 3) * 8;
    b16x8 aR[2], bR[2];
#pragma unroll
    for (int hh = 0; hh < 2; hh++) {
        int r = srow + hh * 64;
        aR[hh] = *(const b16x8*)&Ag[(size_t)r * 128 + scol];
        bR[hh] = *(const b16x8*)&Bg[(size_t)r * 128 + scol];
    }
    for (int k0 = 0; k0 < 128; k0 += 32) {
        if (k0) __syncthreads();
#pragma unroll
        for (int hh = 0; hh < 2; hh++) {
            int r = srow + hh * 64;
            *(b16x8*)&Al[r * 40 + scol] = aR[hh];
            *(b16x8*)&Bl[r * 40 + scol] = bR[hh];
        }
        __syncthreads();
        if (k0 < 96) {
#pragma unroll
            for (int hh = 0; hh < 2; hh++) {
                int r = srow + hh * 64;
                aR[hh] = *(const b16x8*)&Ag[(size_t)r * 128 + k0 + 32 + scol];
                bR[hh] = *(const b16x8*)&Bg[(size_t)r * 128 + k0 + 32 + scol];
            }
        }
        int ko = lg * 8;
        b16x8 af[4], bfr[4];
#pragma unroll
        for (int i = 0; i < 4; i++) af[i]  = *(b16x8*)&Al[(wm * 64 + i * 16 + lr) * 40 + ko];
#pragma unroll
        for (int i = 0; i < 4; i++) bfr[i] = *(b16x8*)&Bl[(wn * 64 + i * 16 + lr) * 40 + ko];
#pragma unroll
        for (int i = 0; i < 4; i++)
#pragma unroll
            for (int j = 0; j < 4; j++)
                acc[i][j] = __builtin_amdgcn_mfma_f32_16x16x32_bf16(af[i], bfr[j], acc[i][j], 0, 0, 0);
    }
    float gm = gamma[0];
    int rbase = lg * 4;
#pragma unroll
    for (int i = 0; i < 4; i++) {
        int m = mt * 128 + wm * 64 + i * 16 + rbase;
#pragma unroll
        for (int j = 0; j < 4; j++) {
            int p = nt * 128 + wn * 64 + j * 16 + lr;
#pragma unroll
            for (int r = 0; r < 4; r++) {
                size_t o = ((size_t)b * 256 + m + r) * 4096 + p;
                __builtin_nontemporal_store(gm * acc[i][j][r] + x[o], &out[o]);
            }
        }
    }
}

extern "C" void kernel_launch(void* const* d_in, const int* in_sizes, int n_in,
                              void* d_out, int out_size, void* d_ws, size_t ws_size,
                              hipStream_t stream) {
    const float* x   = (const float*)d_in[0];
    const float* tw  = (const float*)d_in[1];
    const float* pw  = (const float*)d_in[2];
    const float* gw  = (const float*)d_in[3];
    const float* ow  = (const float*)d_in[4];
    const float* ntw = (const float*)d_in[5];
    const float* ntb = (const float*)d_in[6];
    const float* npw = (const float*)d_in[7];
    const float* npb = (const float*)d_in[8];
    const float* ngw = (const float*)d_in[9];
    const float* ngb = (const float*)d_in[10];
    const float* gamma = (const float*)d_in[11];
    float* out = (float*)d_out;
    char* ws = (char*)d_ws;

    __bf16* Wp  = (__bf16*)(ws + 0);          //  327680 B
    __bf16* OWp = (__bf16*)(ws + 327680);     //  65536 B
    float* tp1  = (float*)(ws + 393216);      //  8*64*256 f32
    float* tp2  = (float*)(ws + 917504);
    float* pp1  = (float*)(ws + 1441792);     //  8*32*256 f32
    float* pp2  = (float*)(ws + 1703936);
    float* gp1  = (float*)(ws + 1966080);     //  8*32*128 f32
    float* gp2  = (float*)(ws + 2097152);
    float* sb   = (float*)(ws + 2228224);     //  10240 f32 scale/bias
    __bf16* th  = (__bf16*)(ws + 2269184);    //  theta_t 16 MB
    __bf16* phk = (__bf16*)(ws + 19046400);   //  pooled phi, K-fragment order, 4 MB
    __bf16* gT  = (__bf16*)(ws + 23240704);   //  pooled g, V-fragment order, 2 MB
    __bf16* om  = (__bf16*)(ws + 25337856);   //  o_mid 8 MB

    float *sct = sb, *bit = sb + 2048, *scp = sb + 4096, *bip = sb + 6144,
          *scg = sb + 8192, *big = sb + 9216;

    prep_weights<<<768, 256, 0, stream>>>(tw, pw, gw, ow, Wp, OWp);
    conv_gemm<<<dim3(32, 5, 8), 256, 0, stream>>>(Wp, x, th, phk, gT,
                                                  tp1, tp2, pp1, pp2, gp1, gp2);
    finalize_stats<<<20, 256, 0, stream>>>(tp1, tp2, pp1, pp2, gp1, gp2,
                                           ntw, ntb, npw, npb, ngw, ngb,
                                           sct, bit, scp, bip, scg, big);
    attn<<<512, 256, 0, stream>>>(th, phk, gT, sct, bit, scp, bip, scg, big, om);
    out_gemm<<<dim3(32, 2, 8), 256, 0, stream>>>(OWp, om, x, gamma, out);
}

// Round 16
// 107.104 us; speedup vs baseline: 1.1190x; 1.1190x over previous
//
#include <hip/hip_runtime.h>
#include <hip/hip_bf16.h>
#include <math.h>

typedef float f32x4 __attribute__((ext_vector_type(4)));
typedef float f32x16 __attribute__((ext_vector_type(16)));
typedef __bf16 b16x8 __attribute__((ext_vector_type(8)));
typedef __bf16 b16x4 __attribute__((ext_vector_type(4)));
typedef unsigned int u32x2 __attribute__((ext_vector_type(2)));
typedef unsigned int u32x4 __attribute__((ext_vector_type(4)));

#define L2E 1.44269504088896340736f

// ---------------------------------------------------------------- weights prep
__global__ void prep_weights(const float* tw, const float* pw, const float* gw,
                             const float* ow, __bf16* Wp, __bf16* OWp) {
    int idx = blockIdx.x * 256 + threadIdx.x;
    if (idx < 640 * 256) {
        int m = idx >> 8, k = idx & 255;
        float v;
        if (m < 256)      { int o = ((m & 63) << 2) + (m >> 6);            v = tw[o * 256 + k]; }
        else if (m < 512) { int mm = m - 256; int o = ((mm & 63) << 2) + (mm >> 6); v = pw[o * 256 + k]; }
        else              { int mm = m - 512; int o = ((mm & 31) << 2) + (mm >> 5); v = gw[o * 256 + k]; }
        Wp[idx] = (__bf16)v;
    } else {
        int j = idx - 640 * 256;
        if (j < 256 * 128) {
            int m = j >> 7, c = j & 127;
            int o = ((c & 31) << 2) + (c >> 5);
            OWp[j] = (__bf16)ow[m * 128 + o];
        }
    }
}

// ---------------- fused conv GEMM + transpose + theta-stats + POOLING epilogue
// mt<2 (theta): stats partials + theta_t write. mt>=2 (phi/g): each block covers
// one image-row-pair = complete 2x2 pool windows -> pool in LDS, write pooled
// RAW values directly in MFMA fragment order + stats partials. K norm folds into
// attention (scp into Q; bias via per-row constant cq added before exp2).
__global__ __launch_bounds__(256) void conv_gemm(const __bf16* __restrict__ Wp,
                                                 const float* __restrict__ x,
                                                 __bf16* theta_t, __bf16* phk, __bf16* gT,
                                                 float* tp1, float* tp2,
                                                 float* pp1, float* pp2,
                                                 float* gp1, float* gp2) {
    __shared__ __align__(16) char smem[38912];
    __bf16* Al = (__bf16*)smem;               // [128][40]
    __bf16* Bl = (__bf16*)(smem + 10240);     // [128][40]
    __bf16* Pl = (__bf16*)smem;               // pooled-phase alias: [128][136]
    float* S1w = (float*)(smem + 34816);      // [4][128]
    float* S2w = (float*)(smem + 36864);      // [4][128]
    int b = blockIdx.z, mt = blockIdx.y, nt = blockIdx.x;
    int tid = threadIdx.x, l = tid & 63, w = tid >> 6;
    int wm = w >> 1, wn = w & 1, lr = l & 15, lg = l >> 4;
    f32x4 acc[4][4];
#pragma unroll
    for (int i = 0; i < 4; i++)
#pragma unroll
        for (int j = 0; j < 4; j++)
#pragma unroll
            for (int r = 0; r < 4; r++) acc[i][j][r] = 0.f;
    const __bf16* Ag = Wp + (size_t)mt * 128 * 256;
    const float* Bx = x + (size_t)b * 1048576 + nt * 128;
    int srow = tid >> 2, scol = (tid & 3) * 8;
    int bn = tid & 127, bk0 = (tid >> 7) * 8;
    b16x8 aR[2];
    float xr[2][8];
#pragma unroll
    for (int hh = 0; hh < 2; hh++)
        aR[hh] = *(const b16x8*)&Ag[(size_t)(srow + hh * 64) * 256 + scol];
#pragma unroll
    for (int u = 0; u < 2; u++)
#pragma unroll
        for (int e = 0; e < 8; e++)
            xr[u][e] = Bx[(size_t)(bk0 + u * 16 + e) * 4096 + bn];
    for (int k0 = 0; k0 < 256; k0 += 32) {
        if (k0) __syncthreads();
#pragma unroll
        for (int hh = 0; hh < 2; hh++)
            *(b16x8*)&Al[(srow + hh * 64) * 40 + scol] = aR[hh];
#pragma unroll
        for (int u = 0; u < 2; u++) {
            b16x8 v;
#pragma unroll
            for (int e = 0; e < 8; e++) v[e] = (__bf16)xr[u][e];
            *(b16x8*)&Bl[bn * 40 + bk0 + u * 16] = v;
        }
        __syncthreads();
        if (k0 < 224) {
#pragma unroll
            for (int hh = 0; hh < 2; hh++)
                aR[hh] = *(const b16x8*)&Ag[(size_t)(srow + hh * 64) * 256 + k0 + 32 + scol];
#pragma unroll
            for (int u = 0; u < 2; u++)
#pragma unroll
                for (int e = 0; e < 8; e++)
                    xr[u][e] = Bx[(size_t)(k0 + 32 + bk0 + u * 16 + e) * 4096 + bn];
        }
        int ko = lg * 8;
        b16x8 af[4], bfr[4];
#pragma unroll
        for (int i = 0; i < 4; i++) af[i]  = *(b16x8*)&Al[(wm * 64 + i * 16 + lr) * 40 + ko];
#pragma unroll
        for (int i = 0; i < 4; i++) bfr[i] = *(b16x8*)&Bl[(wn * 64 + i * 16 + lr) * 40 + ko];
#pragma unroll
        for (int i = 0; i < 4; i++)
#pragma unroll
            for (int j = 0; j < 4; j++)
                acc[i][j] = __builtin_amdgcn_mfma_f32_16x16x32_bf16(af[i], bfr[j], acc[i][j], 0, 0, 0);
    }
    if (mt < 2) {
        // ---- theta: stats partials + full-res transposed write
#pragma unroll
        for (int i = 0; i < 4; i++) {
            float s1v[4], s2v[4];
#pragma unroll
            for (int r = 0; r < 4; r++) {
                float a0 = acc[i][0][r], a1 = acc[i][1][r], a2 = acc[i][2][r], a3 = acc[i][3][r];
                s1v[r] = (a0 + a1) + (a2 + a3);
                s2v[r] = (a0 * a0 + a1 * a1) + (a2 * a2 + a3 * a3);
            }
#pragma unroll
            for (int msk = 1; msk < 16; msk <<= 1)
#pragma unroll
                for (int r = 0; r < 4; r++) {
                    s1v[r] += __shfl_xor(s1v[r], msk, 64);
                    s2v[r] += __shfl_xor(s2v[r], msk, 64);
                }
            if (lr == 0) {
                int row = (b * 32 + nt) * 2 + wn;
#pragma unroll
                for (int r = 0; r < 4; r++) {
                    int ch = mt * 128 + wm * 64 + i * 16 + lg * 4 + r;
                    tp1[row * 256 + ch] = s1v[r];
                    tp2[row * 256 + ch] = s2v[r];
                }
            }
        }
        int rbase = lg * 4;
#pragma unroll
        for (int i = 0; i < 4; i++) {
            int m = mt * 128 + wm * 64 + i * 16 + rbase;
#pragma unroll
            for (int j = 0; j < 4; j++) {
                int p = nt * 128 + wn * 64 + j * 16 + lr;
                b16x4 v;
#pragma unroll
                for (int r = 0; r < 4; r++) v[r] = (__bf16)acc[i][j][r];
                *(b16x4*)&theta_t[((size_t)b * 4096 + p) * 256 + m] = v;
            }
        }
    } else {
        // ---- phi/g: pool 2x2 in LDS, write pooled fragment-order + stats
        __syncthreads();                       // Al/Bl dead -> reuse as Pl
        int rbase = lg * 4;
#pragma unroll
        for (int i = 0; i < 4; i++) {
            int ch = wm * 64 + i * 16 + rbase;
#pragma unroll
            for (int j = 0; j < 4; j++) {
                int p = wn * 64 + j * 16 + lr;
                b16x4 v;
#pragma unroll
                for (int r = 0; r < 4; r++) v[r] = (__bf16)acc[i][j][r];
                *(b16x4*)&Pl[p * 136 + ch] = v;
            }
        }
        __syncthreads();
        int o = tid & 15, tq = tid >> 4;       // o: channel octet; tq: q-pair group
        float a1[8], a2[8];
#pragma unroll
        for (int e = 0; e < 8; e++) { a1[e] = 0.f; a2[e] = 0.f; }
        b16x8 pooled[2];
#pragma unroll
        for (int ss = 0; ss < 2; ss++) {
            int xq = tq * 2 + ss;
            b16x8 v0 = *(b16x8*)&Pl[(2 * xq) * 136 + o * 8];
            b16x8 v1 = *(b16x8*)&Pl[(2 * xq + 1) * 136 + o * 8];
            b16x8 v2 = *(b16x8*)&Pl[(64 + 2 * xq) * 136 + o * 8];
            b16x8 v3 = *(b16x8*)&Pl[(65 + 2 * xq) * 136 + o * 8];
            b16x8 mv;
#pragma unroll
            for (int e = 0; e < 8; e++) {
                float m = fmaxf(fmaxf((float)v0[e], (float)v1[e]), fmaxf((float)v2[e], (float)v3[e]));
                mv[e] = (__bf16)m; a1[e] += m; a2[e] += m * m;
            }
            pooled[ss] = mv;
        }
#pragma unroll
        for (int e = 0; e < 8; e++) {
            a1[e] += __shfl_xor(a1[e], 16, 64); a1[e] += __shfl_xor(a1[e], 32, 64);
            a2[e] += __shfl_xor(a2[e], 16, 64); a2[e] += __shfl_xor(a2[e], 32, 64);
        }
        if ((tid & 63) < 16) {
#pragma unroll
            for (int e = 0; e < 8; e++) {
                S1w[w * 128 + o * 8 + e] = a1[e];
                S2w[w * 128 + o * 8 + e] = a2[e];
            }
        }
        __syncthreads();
        int cc = nt >> 1;
        if (mt < 4) {
            if (tid < 128) {
                float s1 = S1w[tid] + S1w[128 + tid] + S1w[256 + tid] + S1w[384 + tid];
                float s2 = S2w[tid] + S2w[128 + tid] + S2w[256 + tid] + S2w[384 + tid];
                pp1[(size_t)(b * 32 + nt) * 256 + (mt - 2) * 128 + tid] = s1;
                pp2[(size_t)(b * 32 + nt) * 256 + (mt - 2) * 128 + tid] = s2;
            }
            int hh = (mt - 2) * 2 + (o >> 3), slot = o & 7, bh = b * 4 + hh;
#pragma unroll
            for (int ss = 0; ss < 2; ss++) {
                int key = (nt & 1) * 32 + tq * 2 + ss;
                *(b16x8*)&phk[((((size_t)bh * 16 + cc) * 8 + slot) * 64 + key) * 8] = pooled[ss];
            }
        } else {
            if (tid < 128) {
                float s1 = S1w[tid] + S1w[128 + tid] + S1w[256 + tid] + S1w[384 + tid];
                float s2 = S2w[tid] + S2w[128 + tid] + S2w[256 + tid] + S2w[384 + tid];
                gp1[(size_t)(b * 32 + nt) * 128 + tid] = s1;
                gp2[(size_t)(b * 32 + nt) * 128 + tid] = s2;
            }
            // transpose pooled [32 q][128 ch] -> V-fragment order [seg][ch][8 keys]
            __bf16* Pg = Pl;
#pragma unroll
            for (int ss = 0; ss < 2; ss++)
                *(b16x8*)&Pg[(tq * 2 + ss) * 136 + o * 8] = pooled[ss];
            __syncthreads();
            int ch = tid & 127, kg = tid >> 7;
            int hh = ch >> 5, c32 = ch & 31, bh = b * 4 + hh;
#pragma unroll
            for (int gi = 0; gi < 2; gi++) {
                int g2 = kg * 2 + gi;
                b16x8 v;
#pragma unroll
                for (int e = 0; e < 8; e++) v[e] = Pg[(g2 * 8 + e) * 136 + ch];
                int seg = (nt & 1) * 4 + g2;
                *(b16x8*)&gT[((((size_t)bh * 16 + cc) * 8 + seg) * 32 + c32) * 8] = v;
            }
        }
    }
}

// --------------------------------------- sum partials, fold mean/rstd + affine into scale/bias
__global__ void finalize_stats(const float* tp1, const float* tp2, const float* pp1,
                               const float* pp2, const float* gp1, const float* gp2,
                               const float* ntw, const float* ntb, const float* npw,
                               const float* npb, const float* ngw, const float* ngb,
                               float* sct, float* bit, float* scp, float* bip,
                               float* scg, float* big) {
    int idx = blockIdx.x * 256 + threadIdx.x;
    if (idx >= 8 * 640) return;
    int b = idx / 640, c = idx % 640;
    if (c < 256) {
        float s1 = 0.f, s2 = 0.f;
        for (int i = 0; i < 64; i++) { s1 += tp1[(b * 64 + i) * 256 + c]; s2 += tp2[(b * 64 + i) * 256 + c]; }
        float n = 4096.f;
        float m = s1 / n, v = s2 / n - m * m;
        float r = rsqrtf(v + 1e-5f);
        int o = ((c & 63) << 2) + (c >> 6);
        float wv = ntw[o], bv = ntb[o];
        sct[b * 256 + c] = r * wv * L2E;               // log2e folded for exp2-softmax
        bit[b * 256 + c] = (bv - m * r * wv) * L2E;
    } else if (c < 512) {
        int cc = c - 256;
        float s1 = 0.f, s2 = 0.f;
        for (int i = 0; i < 32; i++) { s1 += pp1[(b * 32 + i) * 256 + cc]; s2 += pp2[(b * 32 + i) * 256 + cc]; }
        float n = 1024.f;
        float m = s1 / n, v = s2 / n - m * m;
        float r = rsqrtf(v + 1e-5f);
        int o = ((cc & 63) << 2) + (cc >> 6);
        float wv = npw[o], bv = npb[o];
        scp[b * 256 + cc] = r * wv; bip[b * 256 + cc] = bv - m * r * wv;
    } else {
        int cc = c - 512;
        float s1 = 0.f, s2 = 0.f;
        for (int i = 0; i < 32; i++) { s1 += gp1[(b * 32 + i) * 128 + cc]; s2 += gp2[(b * 32 + i) * 128 + cc]; }
        float n = 1024.f;
        float m = s1 / n, v = s2 / n - m * m;
        float r = rsqrtf(v + 1e-5f);
        int o = ((cc & 31) << 2) + (cc >> 5);
        float wv = ngw[o], bv = ngb[o];
        scg[b * 128 + cc] = r * wv; big[b * 128 + cc] = bv - m * r * wv;
    }
}

// ------------------------------------------- flash attention: R5 structure (best measured)
// K is RAW pooled phi. K-norm scale folds into Q (qf = thn*scp); K-norm bias folds
// into the per-row constant cq = sum(thn*bip), applied as p = exp2(s + cq) to keep
// scores centered. cq stays in 2 scalar VGPRs (broadcast-vector forms spill: R14/R15).
__global__ __launch_bounds__(256, 2) void attn(const __bf16* __restrict__ theta_t,
                                               const __bf16* __restrict__ phk,
                                               const __bf16* __restrict__ gTz,
                                               const float* __restrict__ sct,
                                               const float* __restrict__ bit,
                                               const float* __restrict__ scp,
                                               const float* __restrict__ bip,
                                               const float* __restrict__ scg,
                                               const float* __restrict__ big,
                                               __bf16* __restrict__ o_mid) {
    int bid = blockIdx.x;
    int idx = bid >> 3;
    int bh = (bid & 7) * 4 + (idx >> 4), qt = idx & 15;   // XCD-clustered: 4 bh per XCD
    int b = bh >> 2, h = bh & 3;
    int tid = threadIdx.x, w = tid >> 6, lane = tid & 63;
    int l31 = lane & 31, hi = lane >> 5;
    int qb = qt * 256 + w * 64;

    // Q fragments: thn = sct*theta+bit (log2e folded); qf = thn*scp; cq = sum thn*bip
    b16x8 qf[2][4];
    float cq[2];
#pragma unroll
    for (int m = 0; m < 2; m++) {
        cq[m] = 0.f;
        int q = qb + m * 32 + l31;
        const __bf16* qp = theta_t + ((size_t)b * 4096 + q) * 256 + h * 64;
#pragma unroll
        for (int st = 0; st < 4; st++) {
            int cb = st * 16 + hi * 8;
            b16x8 raw = *(const b16x8*)&qp[cb];
            b16x8 nv;
#pragma unroll
            for (int e = 0; e < 8; e++) {
                int cix = b * 256 + h * 64 + cb + e;
                float thn = (float)raw[e] * sct[cix] + bit[cix];
                cq[m] += thn * bip[cix];
                nv[e] = (__bf16)(thn * scp[cix]);
            }
            qf[m][st] = nv;
        }
        cq[m] += __shfl_xor(cq[m], 32, 64);   // partner half's 32 channels
    }

    const __bf16* Kg = phk + (size_t)bh * 65536 + (size_t)hi * 512 + (size_t)l31 * 8;
    const __bf16* Vg = gTz + (size_t)bh * 32768 + (size_t)hi * 256 + (size_t)l31 * 8;

    f32x16 oacc[2];
    float l_run[2] = {0.f, 0.f};
#pragma unroll
    for (int m = 0; m < 2; m++)
#pragma unroll
        for (int r = 0; r < 16; r++) oacc[m][r] = 0.f;
    f32x16 zc;
#pragma unroll
    for (int r = 0; r < 16; r++) zc[r] = 0.f;

    b16x8 akA[2][4], avA[4], akB[2][4], avB[4];

#define LOADK(dst, c) { _Pragma("unroll") for (int kf = 0; kf < 2; kf++) \
    _Pragma("unroll") for (int st = 0; st < 4; st++) \
        dst[kf][st] = *(const b16x8*)&Kg[(size_t)(c) * 4096 + st * 1024 + kf * 256]; }
#define LOADV(dst, c) { _Pragma("unroll") for (int js = 0; js < 4; js++) \
    dst[js] = *(const b16x8*)&Vg[(size_t)(c) * 2048 + js * 512]; }
#define COMPUTE(ak, av) { \
    _Pragma("unroll") for (int m = 0; m < 2; m++) { \
        float cqm = cq[m]; \
        _Pragma("unroll") for (int kf = 0; kf < 2; kf++) { \
            f32x16 s = __builtin_amdgcn_mfma_f32_32x32x16_bf16(ak[kf][0], qf[m][0], zc, 0, 0, 0); \
            _Pragma("unroll") for (int st = 1; st < 4; st++) \
                s = __builtin_amdgcn_mfma_f32_32x32x16_bf16(ak[kf][st], qf[m][st], s, 0, 0, 0); \
            float sum = 0.f; \
            _Pragma("unroll") for (int r = 0; r < 16; r++) { \
                float p = __builtin_amdgcn_exp2f(s[r] + cqm); s[r] = p; sum += p; } \
            l_run[m] += sum; \
            _Pragma("unroll") for (int hh2 = 0; hh2 < 2; hh2++) { \
                b16x4 A4, B4; \
                _Pragma("unroll") for (int e = 0; e < 4; e++) { \
                    A4[e] = (__bf16)s[hh2 * 8 + e]; B4[e] = (__bf16)s[hh2 * 8 + 4 + e]; } \
                u32x2 a2 = __builtin_bit_cast(u32x2, A4); \
                u32x2 b2 = __builtin_bit_cast(u32x2, B4); \
                u32x2 q0 = __builtin_amdgcn_permlane32_swap(a2[0], b2[0], false, false); \
                u32x2 q1 = __builtin_amdgcn_permlane32_swap(a2[1], b2[1], false, false); \
                u32x4 pd = {q0[0], q1[0], q0[1], q1[1]}; \
                b16x8 pf = __builtin_bit_cast(b16x8, pd); \
                oacc[m] = __builtin_amdgcn_mfma_f32_32x32x16_bf16(av[kf * 2 + hh2], pf, oacc[m], 0, 0, 0); \
            } \
        } \
    } }

    LOADK(akA, 0) LOADV(avA, 0)
#pragma unroll 1
    for (int c = 0; c < 16; c += 2) {
        LOADK(akB, c + 1) LOADV(avB, c + 1)
        COMPUTE(akA, avA)
        if (c + 2 < 16) { LOADK(akA, c + 2) LOADV(avA, c + 2) }
        COMPUTE(akB, avB)
    }
#undef LOADK
#undef LOADV
#undef COMPUTE

    // epilogue: out = scg*(PV/l) + big  (V affine via softmax-sum identity)
#pragma unroll
    for (int m = 0; m < 2; m++) {
        float lr = l_run[m] + __shfl_xor(l_run[m], 32, 64);
        float rl = 1.0f / lr;
        int q = qb + m * 32 + l31;
#pragma unroll
        for (int rr = 0; rr < 4; rr++) {
            b16x4 v;
#pragma unroll
            for (int e = 0; e < 4; e++) {
                int ci = b * 128 + h * 32 + rr * 8 + hi * 4 + e;
                v[e] = (__bf16)(oacc[m][rr * 4 + e] * rl * scg[ci] + big[ci]);
            }
            *(b16x4*)&o_mid[((size_t)b * 4096 + q) * 128 + h * 32 + rr * 8 + hi * 4] = v;
        }
    }
}

// --------------------------------------------- final conv + residual: out = gamma*o + x
__global__ __launch_bounds__(256) void out_gemm(const __bf16* __restrict__ OWp,
                                                const __bf16* __restrict__ o_mid,
                                                const float* __restrict__ x,
                                                const float* gamma, float* out) {
    int b = blockIdx.z, mt = blockIdx.y, nt = blockIdx.x;
    __shared__ __bf16 Al[128 * 40];
    __shared__ __bf16 Bl[128 * 40];
    int tid = threadIdx.x, l = tid & 63, w = tid >> 6;
    int wm = w >> 1, wn = w & 1, lr = l & 15, lg = l >> 4;
    f32x4 acc[4][4];
#pragma unroll
    for (int i = 0; i < 4; i++)
#pragma unroll
        for (int j = 0; j < 4; j++)
#pragma unroll
            for (int r = 0; r < 4; r++) acc[i][j][r] = 0.f;
    const __bf16* Ag = OWp + (size_t)mt * 128 * 128;
    const __bf16* Bg = o_mid + ((size_t)b * 4096 + nt * 128) * 128;
    int srow = tid >> 2, scol = (tid & 3) * 8;
    b16x8 aR[2], bR[2];
#pragma unroll
    for (int hh = 0; hh < 2; hh++) {
        int r = srow + hh * 64;
        aR[hh] = *(const b16x8*)&Ag[(size_t)r * 128 + scol];
        bR[hh] = *(const b16x8*)&Bg[(size_t)r * 128 + scol];
    }
    for (int k0 = 0; k0 < 128; k0 += 32) {
        if (k0) __syncthreads();
#pragma unroll
        for (int hh = 0; hh < 2; hh++) {
            int r = srow + hh * 64;
            *(b16x8*)&Al[r * 40 + scol] = aR[hh];
            *(b16x8*)&Bl[r * 40 + scol] = bR[hh];
        }
        __syncthreads();
        if (k0 < 96) {
#pragma unroll
            for (int hh = 0; hh < 2; hh++) {
                int r = srow + hh * 64;
                aR[hh] = *(const b16x8*)&Ag[(size_t)r * 128 + k0 + 32 + scol];
                bR[hh] = *(const b16x8*)&Bg[(size_t)r * 128 + k0 + 32 + scol];
            }
        }
        int ko = lg * 8;
        b16x8 af[4], bfr[4];
#pragma unroll
        for (int i = 0; i < 4; i++) af[i]  = *(b16x8*)&Al[(wm * 64 + i * 16 + lr) * 40 + ko];
#pragma unroll
        for (int i = 0; i < 4; i++) bfr[i] = *(b16x8*)&Bl[(wn * 64 + i * 16 + lr) * 40 + ko];
#pragma unroll
        for (int i = 0; i < 4; i++)
#pragma unroll
            for (int j = 0; j < 4; j++)
                acc[i][j] = __builtin_amdgcn_mfma_f32_16x16x32_bf16(af[i], bfr[j], acc[i][j], 0, 0, 0);
    }
    float gm = gamma[0];
    int rbase = lg * 4;
#pragma unroll
    for (int i = 0; i < 4; i++) {
        int m = mt * 128 + wm * 64 + i * 16 + rbase;
#pragma unroll
        for (int j = 0; j < 4; j++) {
            int p = nt * 128 + wn * 64 + j * 16 + lr;
#pragma unroll
            for (int r = 0; r < 4; r++) {
                size_t o = ((size_t)b * 256 + m + r) * 4096 + p;
                __builtin_nontemporal_store(gm * acc[i][j][r] + x[o], &out[o]);
            }
        }
    }
}

extern "C" void kernel_launch(void* const* d_in, const int* in_sizes, int n_in,
                              void* d_out, int out_size, void* d_ws, size_t ws_size,
                              hipStream_t stream) {
    const float* x   = (const float*)d_in[0];
    const float* tw  = (const float*)d_in[1];
    const float* pw  = (const float*)d_in[2];
    const float* gw  = (const float*)d_in[3];
    const float* ow  = (const float*)d_in[4];
    const float* ntw = (const float*)d_in[5];
    const float* ntb = (const float*)d_in[6];
    const float* npw = (const float*)d_in[7];
    const float* npb = (const float*)d_in[8];
    const float* ngw = (const float*)d_in[9];
    const float* ngb = (const float*)d_in[10];
    const float* gamma = (const float*)d_in[11];
    float* out = (float*)d_out;
    char* ws = (char*)d_ws;

    __bf16* Wp  = (__bf16*)(ws + 0);          //  327680 B
    __bf16* OWp = (__bf16*)(ws + 327680);     //  65536 B
    float* tp1  = (float*)(ws + 393216);      //  8*64*256 f32
    float* tp2  = (float*)(ws + 917504);
    float* pp1  = (float*)(ws + 1441792);     //  8*32*256 f32
    float* pp2  = (float*)(ws + 1703936);
    float* gp1  = (float*)(ws + 1966080);     //  8*32*128 f32
    float* gp2  = (float*)(ws + 2097152);
    float* sb   = (float*)(ws + 2228224);     //  10240 f32 scale/bias
    __bf16* th  = (__bf16*)(ws + 2269184);    //  theta_t 16 MB
    __bf16* phk = (__bf16*)(ws + 19046400);   //  pooled phi, K-fragment order, 4 MB
    __bf16* gT  = (__bf16*)(ws + 23240704);   //  pooled g, V-fragment order, 2 MB
    __bf16* om  = (__bf16*)(ws + 25337856);   //  o_mid 8 MB

    float *sct = sb, *bit = sb + 2048, *scp = sb + 4096, *bip = sb + 6144,
          *scg = sb + 8192, *big = sb + 9216;

    prep_weights<<<768, 256, 0, stream>>>(tw, pw, gw, ow, Wp, OWp);
    conv_gemm<<<dim3(32, 5, 8), 256, 0, stream>>>(Wp, x, th, phk, gT,
                                                  tp1, tp2, pp1, pp2, gp1, gp2);
    finalize_stats<<<20, 256, 0, stream>>>(tp1, tp2, pp1, pp2, gp1, gp2,
                                           ntw, ntb, npw, npb, ngw, ngb,
                                           sct, bit, scp, bip, scg, big);
    attn<<<512, 256, 0, stream>>>(th, phk, gT, sct, bit, scp, bip, scg, big, om);
    out_gemm<<<dim3(32, 2, 8), 256, 0, stream>>>(OWp, om, x, gamma, out);
}

// Round 17
// 104.976 us; speedup vs baseline: 1.1417x; 1.0203x over previous
//
#include <hip/hip_runtime.h>
#include <hip/hip_bf16.h>
#include <math.h>

typedef float f32x4 __attribute__((ext_vector_type(4)));
typedef float f32x16 __attribute__((ext_vector_type(16)));
typedef __bf16 b16x8 __attribute__((ext_vector_type(8)));
typedef __bf16 b16x4 __attribute__((ext_vector_type(4)));
typedef unsigned int u32x2 __attribute__((ext_vector_type(2)));
typedef unsigned int u32x4 __attribute__((ext_vector_type(4)));

#define L2E 1.44269504088896340736f

// ---------------------------------------------------------------- weights prep
__global__ void prep_weights(const float* tw, const float* pw, const float* gw,
                             const float* ow, __bf16* Wp, __bf16* OWp) {
    int idx = blockIdx.x * 256 + threadIdx.x;
    if (idx < 640 * 256) {
        int m = idx >> 8, k = idx & 255;
        float v;
        if (m < 256)      { int o = ((m & 63) << 2) + (m >> 6);            v = tw[o * 256 + k]; }
        else if (m < 512) { int mm = m - 256; int o = ((mm & 63) << 2) + (mm >> 6); v = pw[o * 256 + k]; }
        else              { int mm = m - 512; int o = ((mm & 31) << 2) + (mm >> 5); v = gw[o * 256 + k]; }
        Wp[idx] = (__bf16)v;
    } else {
        int j = idx - 640 * 256;
        if (j < 256 * 128) {
            int m = j >> 7, c = j & 127;
            int o = ((c & 31) << 2) + (c >> 5);
            OWp[j] = (__bf16)ow[m * 128 + o];
        }
    }
}

// ---------------- fused conv GEMM + transpose + theta-stats + POOLING epilogue
// mt<2 (theta): stats partials + theta_t write. mt>=2 (phi/g): each block covers
// one image-row-pair = complete 2x2 pool windows -> pool in LDS, write pooled
// RAW values directly in MFMA fragment order + stats partials.
__global__ __launch_bounds__(256) void conv_gemm(const __bf16* __restrict__ Wp,
                                                 const float* __restrict__ x,
                                                 __bf16* theta_t, __bf16* phk, __bf16* gT,
                                                 float* tp1, float* tp2,
                                                 float* pp1, float* pp2,
                                                 float* gp1, float* gp2) {
    __shared__ __align__(16) char smem[38912];
    __bf16* Al = (__bf16*)smem;               // [128][40]
    __bf16* Bl = (__bf16*)(smem + 10240);     // [128][40]
    __bf16* Pl = (__bf16*)smem;               // pooled-phase alias: [128][136]
    float* S1w = (float*)(smem + 34816);      // [4][128]
    float* S2w = (float*)(smem + 36864);      // [4][128]
    int b = blockIdx.z, mt = blockIdx.y, nt = blockIdx.x;
    int tid = threadIdx.x, l = tid & 63, w = tid >> 6;
    int wm = w >> 1, wn = w & 1, lr = l & 15, lg = l >> 4;
    f32x4 acc[4][4];
#pragma unroll
    for (int i = 0; i < 4; i++)
#pragma unroll
        for (int j = 0; j < 4; j++)
#pragma unroll
            for (int r = 0; r < 4; r++) acc[i][j][r] = 0.f;
    const __bf16* Ag = Wp + (size_t)mt * 128 * 256;
    const float* Bx = x + (size_t)b * 1048576 + nt * 128;
    int srow = tid >> 2, scol = (tid & 3) * 8;
    int bn = tid & 127, bk0 = (tid >> 7) * 8;
    b16x8 aR[2];
    float xr[2][8];
#pragma unroll
    for (int hh = 0; hh < 2; hh++)
        aR[hh] = *(const b16x8*)&Ag[(size_t)(srow + hh * 64) * 256 + scol];
#pragma unroll
    for (int u = 0; u < 2; u++)
#pragma unroll
        for (int e = 0; e < 8; e++)
            xr[u][e] = Bx[(size_t)(bk0 + u * 16 + e) * 4096 + bn];
    for (int k0 = 0; k0 < 256; k0 += 32) {
        if (k0) __syncthreads();
#pragma unroll
        for (int hh = 0; hh < 2; hh++)
            *(b16x8*)&Al[(srow + hh * 64) * 40 + scol] = aR[hh];
#pragma unroll
        for (int u = 0; u < 2; u++) {
            b16x8 v;
#pragma unroll
            for (int e = 0; e < 8; e++) v[e] = (__bf16)xr[u][e];
            *(b16x8*)&Bl[bn * 40 + bk0 + u * 16] = v;
        }
        __syncthreads();
        if (k0 < 224) {
#pragma unroll
            for (int hh = 0; hh < 2; hh++)
                aR[hh] = *(const b16x8*)&Ag[(size_t)(srow + hh * 64) * 256 + k0 + 32 + scol];
#pragma unroll
            for (int u = 0; u < 2; u++)
#pragma unroll
                for (int e = 0; e < 8; e++)
                    xr[u][e] = Bx[(size_t)(k0 + 32 + bk0 + u * 16 + e) * 4096 + bn];
        }
        int ko = lg * 8;
        b16x8 af[4], bfr[4];
#pragma unroll
        for (int i = 0; i < 4; i++) af[i]  = *(b16x8*)&Al[(wm * 64 + i * 16 + lr) * 40 + ko];
#pragma unroll
        for (int i = 0; i < 4; i++) bfr[i] = *(b16x8*)&Bl[(wn * 64 + i * 16 + lr) * 40 + ko];
#pragma unroll
        for (int i = 0; i < 4; i++)
#pragma unroll
            for (int j = 0; j < 4; j++)
                acc[i][j] = __builtin_amdgcn_mfma_f32_16x16x32_bf16(af[i], bfr[j], acc[i][j], 0, 0, 0);
    }
    if (mt < 2) {
        // ---- theta: stats partials + full-res transposed write
#pragma unroll
        for (int i = 0; i < 4; i++) {
            float s1v[4], s2v[4];
#pragma unroll
            for (int r = 0; r < 4; r++) {
                float a0 = acc[i][0][r], a1 = acc[i][1][r], a2 = acc[i][2][r], a3 = acc[i][3][r];
                s1v[r] = (a0 + a1) + (a2 + a3);
                s2v[r] = (a0 * a0 + a1 * a1) + (a2 * a2 + a3 * a3);
            }
#pragma unroll
            for (int msk = 1; msk < 16; msk <<= 1)
#pragma unroll
                for (int r = 0; r < 4; r++) {
                    s1v[r] += __shfl_xor(s1v[r], msk, 64);
                    s2v[r] += __shfl_xor(s2v[r], msk, 64);
                }
            if (lr == 0) {
                int row = (b * 32 + nt) * 2 + wn;
#pragma unroll
                for (int r = 0; r < 4; r++) {
                    int ch = mt * 128 + wm * 64 + i * 16 + lg * 4 + r;
                    tp1[row * 256 + ch] = s1v[r];
                    tp2[row * 256 + ch] = s2v[r];
                }
            }
        }
        int rbase = lg * 4;
#pragma unroll
        for (int i = 0; i < 4; i++) {
            int m = mt * 128 + wm * 64 + i * 16 + rbase;
#pragma unroll
            for (int j = 0; j < 4; j++) {
                int p = nt * 128 + wn * 64 + j * 16 + lr;
                b16x4 v;
#pragma unroll
                for (int r = 0; r < 4; r++) v[r] = (__bf16)acc[i][j][r];
                *(b16x4*)&theta_t[((size_t)b * 4096 + p) * 256 + m] = v;
            }
        }
    } else {
        // ---- phi/g: pool 2x2 in LDS, write pooled fragment-order + stats
        __syncthreads();                       // Al/Bl dead -> reuse as Pl
        int rbase = lg * 4;
#pragma unroll
        for (int i = 0; i < 4; i++) {
            int ch = wm * 64 + i * 16 + rbase;
#pragma unroll
            for (int j = 0; j < 4; j++) {
                int p = wn * 64 + j * 16 + lr;
                b16x4 v;
#pragma unroll
                for (int r = 0; r < 4; r++) v[r] = (__bf16)acc[i][j][r];
                *(b16x4*)&Pl[p * 136 + ch] = v;
            }
        }
        __syncthreads();
        int o = tid & 15, tq = tid >> 4;       // o: channel octet; tq: q-pair group
        float a1[8], a2[8];
#pragma unroll
        for (int e = 0; e < 8; e++) { a1[e] = 0.f; a2[e] = 0.f; }
        b16x8 pooled[2];
#pragma unroll
        for (int ss = 0; ss < 2; ss++) {
            int xq = tq * 2 + ss;
            b16x8 v0 = *(b16x8*)&Pl[(2 * xq) * 136 + o * 8];
            b16x8 v1 = *(b16x8*)&Pl[(2 * xq + 1) * 136 + o * 8];
            b16x8 v2 = *(b16x8*)&Pl[(64 + 2 * xq) * 136 + o * 8];
            b16x8 v3 = *(b16x8*)&Pl[(65 + 2 * xq) * 136 + o * 8];
            b16x8 mv;
#pragma unroll
            for (int e = 0; e < 8; e++) {
                float m = fmaxf(fmaxf((float)v0[e], (float)v1[e]), fmaxf((float)v2[e], (float)v3[e]));
                mv[e] = (__bf16)m; a1[e] += m; a2[e] += m * m;
            }
            pooled[ss] = mv;
        }
#pragma unroll
        for (int e = 0; e < 8; e++) {
            a1[e] += __shfl_xor(a1[e], 16, 64); a1[e] += __shfl_xor(a1[e], 32, 64);
            a2[e] += __shfl_xor(a2[e], 16, 64); a2[e] += __shfl_xor(a2[e], 32, 64);
        }
        if ((tid & 63) < 16) {
#pragma unroll
            for (int e = 0; e < 8; e++) {
                S1w[w * 128 + o * 8 + e] = a1[e];
                S2w[w * 128 + o * 8 + e] = a2[e];
            }
        }
        __syncthreads();
        int cc = nt >> 1;
        if (mt < 4) {
            if (tid < 128) {
                float s1 = S1w[tid] + S1w[128 + tid] + S1w[256 + tid] + S1w[384 + tid];
                float s2 = S2w[tid] + S2w[128 + tid] + S2w[256 + tid] + S2w[384 + tid];
                pp1[(size_t)(b * 32 + nt) * 256 + (mt - 2) * 128 + tid] = s1;
                pp2[(size_t)(b * 32 + nt) * 256 + (mt - 2) * 128 + tid] = s2;
            }
            int hh = (mt - 2) * 2 + (o >> 3), slot = o & 7, bh = b * 4 + hh;
#pragma unroll
            for (int ss = 0; ss < 2; ss++) {
                int key = (nt & 1) * 32 + tq * 2 + ss;
                *(b16x8*)&phk[((((size_t)bh * 16 + cc) * 8 + slot) * 64 + key) * 8] = pooled[ss];
            }
        } else {
            if (tid < 128) {
                float s1 = S1w[tid] + S1w[128 + tid] + S1w[256 + tid] + S1w[384 + tid];
                float s2 = S2w[tid] + S2w[128 + tid] + S2w[256 + tid] + S2w[384 + tid];
                gp1[(size_t)(b * 32 + nt) * 128 + tid] = s1;
                gp2[(size_t)(b * 32 + nt) * 128 + tid] = s2;
            }
            // transpose pooled [32 q][128 ch] -> V-fragment order [seg][ch][8 keys]
            __bf16* Pg = Pl;
#pragma unroll
            for (int ss = 0; ss < 2; ss++)
                *(b16x8*)&Pg[(tq * 2 + ss) * 136 + o * 8] = pooled[ss];
            __syncthreads();
            int ch = tid & 127, kg = tid >> 7;
            int hh = ch >> 5, c32 = ch & 31, bh = b * 4 + hh;
#pragma unroll
            for (int gi = 0; gi < 2; gi++) {
                int g2 = kg * 2 + gi;
                b16x8 v;
#pragma unroll
                for (int e = 0; e < 8; e++) v[e] = Pg[(g2 * 8 + e) * 136 + ch];
                int seg = (nt & 1) * 4 + g2;
                *(b16x8*)&gT[((((size_t)bh * 16 + cc) * 8 + seg) * 32 + c32) * 8] = v;
            }
        }
    }
}

// --------------------------------------- sum partials, fold mean/rstd + affine into scale/bias
__global__ void finalize_stats(const float* tp1, const float* tp2, const float* pp1,
                               const float* pp2, const float* gp1, const float* gp2,
                               const float* ntw, const float* ntb, const float* npw,
                               const float* npb, const float* ngw, const float* ngb,
                               float* sct, float* bit, float* scp, float* bip,
                               float* scg, float* big) {
    int idx = blockIdx.x * 256 + threadIdx.x;
    if (idx >= 8 * 640) return;
    int b = idx / 640, c = idx % 640;
    if (c < 256) {
        float s1 = 0.f, s2 = 0.f;
        for (int i = 0; i < 64; i++) { s1 += tp1[(b * 64 + i) * 256 + c]; s2 += tp2[(b * 64 + i) * 256 + c]; }
        float n = 4096.f;
        float m = s1 / n, v = s2 / n - m * m;
        float r = rsqrtf(v + 1e-5f);
        int o = ((c & 63) << 2) + (c >> 6);
        float wv = ntw[o], bv = ntb[o];
        sct[b * 256 + c] = r * wv * L2E;               // log2e folded for exp2-softmax
        bit[b * 256 + c] = (bv - m * r * wv) * L2E;
    } else if (c < 512) {
        int cc = c - 256;
        float s1 = 0.f, s2 = 0.f;
        for (int i = 0; i < 32; i++) { s1 += pp1[(b * 32 + i) * 256 + cc]; s2 += pp2[(b * 32 + i) * 256 + cc]; }
        float n = 1024.f;
        float m = s1 / n, v = s2 / n - m * m;
        float r = rsqrtf(v + 1e-5f);
        int o = ((cc & 63) << 2) + (cc >> 6);
        float wv = npw[o], bv = npb[o];
        scp[b * 256 + cc] = r * wv; bip[b * 256 + cc] = bv - m * r * wv;
    } else {
        int cc = c - 512;
        float s1 = 0.f, s2 = 0.f;
        for (int i = 0; i < 32; i++) { s1 += gp1[(b * 32 + i) * 128 + cc]; s2 += gp2[(b * 32 + i) * 128 + cc]; }
        float n = 1024.f;
        float m = s1 / n, v = s2 / n - m * m;
        float r = rsqrtf(v + 1e-5f);
        int o = ((cc & 31) << 2) + (cc >> 5);
        float wv = ngw[o], bv = ngb[o];
        scg[b * 128 + cc] = r * wv; big[b * 128 + cc] = bv - m * r * wv;
    }
}

// ---------- normalize phk IN PLACE (4 MB): channel = h*64 + (slot>>1)*16 + (slot&1)*8 + e
// Removes the per-chunk bias adds from attn (R11 inner loop = measured fastest).
__global__ void normalize_phk(__bf16* __restrict__ phk,
                              const float* __restrict__ scp,
                              const float* __restrict__ bip) {
    int u = blockIdx.x * 256 + threadIdx.x;        // b16x8 unit index, 262144 total
    int bh = u >> 13, slot = (u >> 6) & 7;
    int b = bh >> 2, h = bh & 3;
    int cf = b * 256 + h * 64 + (slot >> 1) * 16 + (slot & 1) * 8;
    size_t off = (size_t)u * 8;
    b16x8 v = *(b16x8*)&phk[off];
    b16x8 nv;
#pragma unroll
    for (int e = 0; e < 8; e++)
        nv[e] = (__bf16)((float)v[e] * scp[cf + e] + bip[cf + e]);
    *(b16x8*)&phk[off] = nv;
}

// ------------------------------------------- flash attention: R5/R11 structure (fastest)
// K pre-normalized (normalize_phk). Barrier-free, LDS-free, m=2, register ping-pong,
// no max tracking (p = exp2(s), scale-invariant). V raw, affine in epilogue.
__global__ __launch_bounds__(256, 2) void attn(const __bf16* __restrict__ theta_t,
                                               const __bf16* __restrict__ phk,
                                               const __bf16* __restrict__ gTz,
                                               const float* __restrict__ sct,
                                               const float* __restrict__ bit,
                                               const float* __restrict__ scg,
                                               const float* __restrict__ big,
                                               __bf16* __restrict__ o_mid) {
    int bid = blockIdx.x;
    int idx = bid >> 3;
    int bh = (bid & 7) * 4 + (idx >> 4), qt = idx & 15;   // XCD-clustered: 4 bh per XCD
    int b = bh >> 2, h = bh & 3;
    int tid = threadIdx.x, w = tid >> 6, lane = tid & 63;
    int l31 = lane & 31, hi = lane >> 5;
    int qb = qt * 256 + w * 64;

    // Q fragments (normalized + log2e-scaled): B[j=q][c], lane(q=l31,hi) holds c=st*16+hi*8+e
    b16x8 qf[2][4];
#pragma unroll
    for (int m = 0; m < 2; m++) {
        int q = qb + m * 32 + l31;
        const __bf16* qp = theta_t + ((size_t)b * 4096 + q) * 256 + h * 64;
#pragma unroll
        for (int st = 0; st < 4; st++) {
            int cb = st * 16 + hi * 8;
            b16x8 raw = *(const b16x8*)&qp[cb];
            b16x8 nv;
#pragma unroll
            for (int e = 0; e < 8; e++) {
                int cix = b * 256 + h * 64 + cb + e;
                nv[e] = (__bf16)((float)raw[e] * sct[cix] + bit[cix]);
            }
            qf[m][st] = nv;
        }
    }

    const __bf16* Kg = phk + (size_t)bh * 65536 + (size_t)hi * 512 + (size_t)l31 * 8;
    const __bf16* Vg = gTz + (size_t)bh * 32768 + (size_t)hi * 256 + (size_t)l31 * 8;

    f32x16 oacc[2];
    float l_run[2] = {0.f, 0.f};
#pragma unroll
    for (int m = 0; m < 2; m++)
#pragma unroll
        for (int r = 0; r < 16; r++) oacc[m][r] = 0.f;
    f32x16 zc;
#pragma unroll
    for (int r = 0; r < 16; r++) zc[r] = 0.f;

    b16x8 akA[2][4], avA[4], akB[2][4], avB[4];

#define LOADK(dst, c) { _Pragma("unroll") for (int kf = 0; kf < 2; kf++) \
    _Pragma("unroll") for (int st = 0; st < 4; st++) \
        dst[kf][st] = *(const b16x8*)&Kg[(size_t)(c) * 4096 + st * 1024 + kf * 256]; }
#define LOADV(dst, c) { _Pragma("unroll") for (int js = 0; js < 4; js++) \
    dst[js] = *(const b16x8*)&Vg[(size_t)(c) * 2048 + js * 512]; }
#define COMPUTE(ak, av) { \
    _Pragma("unroll") for (int m = 0; m < 2; m++) { \
        _Pragma("unroll") for (int kf = 0; kf < 2; kf++) { \
            f32x16 s = __builtin_amdgcn_mfma_f32_32x32x16_bf16(ak[kf][0], qf[m][0], zc, 0, 0, 0); \
            _Pragma("unroll") for (int st = 1; st < 4; st++) \
                s = __builtin_amdgcn_mfma_f32_32x32x16_bf16(ak[kf][st], qf[m][st], s, 0, 0, 0); \
            float sum = 0.f; \
            _Pragma("unroll") for (int r = 0; r < 16; r++) { \
                float p = __builtin_amdgcn_exp2f(s[r]); s[r] = p; sum += p; } \
            l_run[m] += sum; \
            _Pragma("unroll") for (int hh2 = 0; hh2 < 2; hh2++) { \
                b16x4 A4, B4; \
                _Pragma("unroll") for (int e = 0; e < 4; e++) { \
                    A4[e] = (__bf16)s[hh2 * 8 + e]; B4[e] = (__bf16)s[hh2 * 8 + 4 + e]; } \
                u32x2 a2 = __builtin_bit_cast(u32x2, A4); \
                u32x2 b2 = __builtin_bit_cast(u32x2, B4); \
                u32x2 q0 = __builtin_amdgcn_permlane32_swap(a2[0], b2[0], false, false); \
                u32x2 q1 = __builtin_amdgcn_permlane32_swap(a2[1], b2[1], false, false); \
                u32x4 pd = {q0[0], q1[0], q0[1], q1[1]}; \
                b16x8 pf = __builtin_bit_cast(b16x8, pd); \
                oacc[m] = __builtin_amdgcn_mfma_f32_32x32x16_bf16(av[kf * 2 + hh2], pf, oacc[m], 0, 0, 0); \
            } \
        } \
    } }

    LOADK(akA, 0) LOADV(avA, 0)
#pragma unroll 1
    for (int c = 0; c < 16; c += 2) {
        LOADK(akB, c + 1) LOADV(avB, c + 1)
        COMPUTE(akA, avA)
        if (c + 2 < 16) { LOADK(akA, c + 2) LOADV(avA, c + 2) }
        COMPUTE(akB, avB)
    }
#undef LOADK
#undef LOADV
#undef COMPUTE

    // epilogue: out = scg*(PV/l) + big  (V affine via softmax-sum identity)
#pragma unroll
    for (int m = 0; m < 2; m++) {
        float lr = l_run[m] + __shfl_xor(l_run[m], 32, 64);
        float rl = 1.0f / lr;
        int q = qb + m * 32 + l31;
#pragma unroll
        for (int rr = 0; rr < 4; rr++) {
            b16x4 v;
#pragma unroll
            for (int e = 0; e < 4; e++) {
                int ci = b * 128 + h * 32 + rr * 8 + hi * 4 + e;
                v[e] = (__bf16)(oacc[m][rr * 4 + e] * rl * scg[ci] + big[ci]);
            }
            *(b16x4*)&o_mid[((size_t)b * 4096 + q) * 128 + h * 32 + rr * 8 + hi * 4] = v;
        }
    }
}

// --------------------------------------------- final conv + residual: out = gamma*o + x
__global__ __launch_bounds__(256) void out_gemm(const __bf16* __restrict__ OWp,
                                                const __bf16* __restrict__ o_mid,
                                                const float* __restrict__ x,
                                                const float* gamma, float* out) {
    int b = blockIdx.z, mt = blockIdx.y, nt = blockIdx.x;
    __shared__ __bf16 Al[128 * 40];
    __shared__ __bf16 Bl[128 * 40];
    int tid = threadIdx.x, l = tid & 63, w = tid >> 6;
    int wm = w >> 1, wn = w & 1, lr = l & 15, lg = l >> 4;
    f32x4 acc[4][4];
#pragma unroll
    for (int i = 0; i < 4; i++)
#pragma unroll
        for (int j = 0; j < 4; j++)
#pragma unroll
            for (int r = 0; r < 4; r++) acc[i][j][r] = 0.f;
    const __bf16* Ag = OWp + (size_t)mt * 128 * 128;
    const __bf16* Bg = o_mid + ((size_t)b * 4096 + nt * 128) * 128;
    int srow = tid >> 2, scol = (tid & 3) * 8;
    b16x8 aR[2], bR[2];
#pragma unroll
    for (int hh = 0; hh < 2; hh++) {
        int r = srow + hh * 64;
        aR[hh] = *(const b16x8*)&Ag[(size_t)r * 128 + scol];
        bR[hh] = *(const b16x8*)&Bg[(size_t)r * 128 + scol];
    }
    for (int k0 = 0; k0 < 128; k0 += 32) {
        if (k0) __syncthreads();
#pragma unroll
        for (int hh = 0; hh < 2; hh++) {
            int r = srow + hh * 64;
            *(b16x8*)&Al[r * 40 + scol] = aR[hh];
            *(b16x8*)&Bl[r * 40 + scol] = bR[hh];
        }
        __syncthreads();
        if (k0 < 96) {
#pragma unroll
            for (int hh = 0; hh < 2; hh++) {
                int r = srow + hh * 64;
                aR[hh] = *(const b16x8*)&Ag[(size_t)r * 128 + k0 + 32 + scol];
                bR[hh] = *(const b16x8*)&Bg[(size_t)r * 128 + k0 + 32 + scol];
            }
        }
        int ko = lg * 8;
        b16x8 af[4], bfr[4];
#pragma unroll
        for (int i = 0; i < 4; i++) af[i]  = *(b16x8*)&Al[(wm * 64 + i * 16 + lr) * 40 + ko];
#pragma unroll
        for (int i = 0; i < 4; i++) bfr[i] = *(b16x8*)&Bl[(wn * 64 + i * 16 + lr) * 40 + ko];
#pragma unroll
        for (int i = 0; i < 4; i++)
#pragma unroll
            for (int j = 0; j < 4; j++)
                acc[i][j] = __builtin_amdgcn_mfma_f32_16x16x32_bf16(af[i], bfr[j], acc[i][j], 0, 0, 0);
    }
    float gm = gamma[0];
    int rbase = lg * 4;
#pragma unroll
    for (int i = 0; i < 4; i++) {
        int m = mt * 128 + wm * 64 + i * 16 + rbase;
#pragma unroll
        for (int j = 0; j < 4; j++) {
            int p = nt * 128 + wn * 64 + j * 16 + lr;
#pragma unroll
            for (int r = 0; r < 4; r++) {
                size_t o = ((size_t)b * 256 + m + r) * 4096 + p;
                __builtin_nontemporal_store(gm * acc[i][j][r] + x[o], &out[o]);
            }
        }
    }
}

extern "C" void kernel_launch(void* const* d_in, const int* in_sizes, int n_in,
                              void* d_out, int out_size, void* d_ws, size_t ws_size,
                              hipStream_t stream) {
    const float* x   = (const float*)d_in[0];
    const float* tw  = (const float*)d_in[1];
    const float* pw  = (const float*)d_in[2];
    const float* gw  = (const float*)d_in[3];
    const float* ow  = (const float*)d_in[4];
    const float* ntw = (const float*)d_in[5];
    const float* ntb = (const float*)d_in[6];
    const float* npw = (const float*)d_in[7];
    const float* npb = (const float*)d_in[8];
    const float* ngw = (const float*)d_in[9];
    const float* ngb = (const float*)d_in[10];
    const float* gamma = (const float*)d_in[11];
    float* out = (float*)d_out;
    char* ws = (char*)d_ws;

    __bf16* Wp  = (__bf16*)(ws + 0);          //  327680 B
    __bf16* OWp = (__bf16*)(ws + 327680);     //  65536 B
    float* tp1  = (float*)(ws + 393216);      //  8*64*256 f32
    float* tp2  = (float*)(ws + 917504);
    float* pp1  = (float*)(ws + 1441792);     //  8*32*256 f32
    float* pp2  = (float*)(ws + 1703936);
    float* gp1  = (float*)(ws + 1966080);     //  8*32*128 f32
    float* gp2  = (float*)(ws + 2097152);
    float* sb   = (float*)(ws + 2228224);     //  10240 f32 scale/bias
    __bf16* th  = (__bf16*)(ws + 2269184);    //  theta_t 16 MB
    __bf16* phk = (__bf16*)(ws + 19046400);   //  pooled phi, K-fragment order, 4 MB
    __bf16* gT  = (__bf16*)(ws + 23240704);   //  pooled g, V-fragment order, 2 MB
    __bf16* om  = (__bf16*)(ws + 25337856);   //  o_mid 8 MB

    float *sct = sb, *bit = sb + 2048, *scp = sb + 4096, *bip = sb + 6144,
          *scg = sb + 8192, *big = sb + 9216;

    prep_weights<<<768, 256, 0, stream>>>(tw, pw, gw, ow, Wp, OWp);
    conv_gemm<<<dim3(32, 5, 8), 256, 0, stream>>>(Wp, x, th, phk, gT,
                                                  tp1, tp2, pp1, pp2, gp1, gp2);
    finalize_stats<<<20, 256, 0, stream>>>(tp1, tp2, pp1, pp2, gp1, gp2,
                                           ntw, ntb, npw, npb, ngw, ngb,
                                           sct, bit, scp, bip, scg, big);
    normalize_phk<<<1024, 256, 0, stream>>>(phk, scp, bip);
    attn<<<512, 256, 0, stream>>>(th, phk, gT, sct, bit, scg, big, om);
    out_gemm<<<dim3(32, 2, 8), 256, 0, stream>>>(OWp, om, x, gamma, out);
}